// Round 2
// baseline (521.844 us; speedup 1.0000x reference)
//
#include <hip/hip_runtime.h>
#include <cstddef>

typedef __bf16 bf16;
typedef __bf16 bf16x8 __attribute__((ext_vector_type(8)));
typedef short  s16x8  __attribute__((ext_vector_type(8)));
typedef float  f32x4  __attribute__((ext_vector_type(4)));

// ---------------------------------------------------------------------------
// MFMA wrapper robust to builtin operand type (__bf16 vector vs short vector)
// ---------------------------------------------------------------------------
template <class T> T&& declv() noexcept;
template <class, class = void> struct takes_bf16vec { static constexpr bool value = false; };
template <class V> struct takes_bf16vec<V, decltype((void)__builtin_amdgcn_mfma_f32_16x16x32_bf16(
    declv<V>(), declv<V>(), declv<f32x4>(), 0, 0, 0))> { static constexpr bool value = true; };

template <class V>
__device__ __forceinline__ f32x4 mfma_bf16_16x16x32(V a, V b, f32x4 c) {
  if constexpr (takes_bf16vec<V>::value) {
    return __builtin_amdgcn_mfma_f32_16x16x32_bf16(a, b, c, 0, 0, 0);
  } else {
    return __builtin_amdgcn_mfma_f32_16x16x32_bf16(
        __builtin_bit_cast(s16x8, a), __builtin_bit_cast(s16x8, b), c, 0, 0, 0);
  }
}

constexpr int M_NONE = 0, M_SILU = 1, M_SIG = 2, M_SCALE = 3, M_FINAL = 4;
constexpr int FLAG_BD = 1, FLAG_S4 = 2;

// ---------------------------------------------------------------------------
// LayerNorm: x[64][1024] f32 -> xn bf16 (fp32 math, two-pass like the ref)
// ---------------------------------------------------------------------------
__global__ __launch_bounds__(256) void ln_kernel(const float* __restrict__ x,
                                                 const float* __restrict__ w,
                                                 const float* __restrict__ bs,
                                                 bf16* __restrict__ xn) {
  const int b = blockIdx.x, tid = threadIdx.x;
  __shared__ float red[256];
  float vals[4];
  float s = 0.f;
#pragma unroll
  for (int i = 0; i < 4; ++i) { vals[i] = x[b * 1024 + i * 256 + tid]; s += vals[i]; }
  red[tid] = s; __syncthreads();
  for (int off = 128; off; off >>= 1) { if (tid < off) red[tid] += red[tid + off]; __syncthreads(); }
  const float mu = red[0] * (1.f / 1024.f);
  __syncthreads();
  float s2 = 0.f;
#pragma unroll
  for (int i = 0; i < 4; ++i) { const float d = vals[i] - mu; s2 += d * d; }
  red[tid] = s2; __syncthreads();
  for (int off = 128; off; off >>= 1) { if (tid < off) red[tid] += red[tid + off]; __syncthreads(); }
  const float rs = rsqrtf(red[0] * (1.f / 1024.f) + 1e-5f);
#pragma unroll
  for (int i = 0; i < 4; ++i) {
    const int j = i * 256 + tid;
    xn[b * 1024 + j] = (bf16)((vals[i] - mu) * rs * w[j] + bs[j]);
  }
}

// ---------------------------------------------------------------------------
// Skinny MFMA GEMM: C[64][N] = epilogue(A[64][K] @ B + bias)
//   A: bf16 [64][ldA].  B: f32, converted to bf16 in-flight.
//   flags&FLAG_BD: block-diagonal per-head (Keff=256, W=[8][256][256])
//   flags&FLAG_S4: B[n][k] = W[(n*2048+k)*4 + 3]  (conv tap, stride-4 f32)
//   else:          B stored [K][N] row-major f32
// Block = 256 threads = 4 waves; wave w takes K-chunk w; LDS split-K combine.
// ---------------------------------------------------------------------------
__global__ __launch_bounds__(256) void gemm_sk(
    const bf16* __restrict__ A, const float* __restrict__ W,
    const float* __restrict__ bias, const float* __restrict__ xadd,
    float* __restrict__ outF, bf16* __restrict__ outB,
    int K, int N, int ldA, int mode, int flags) {
  const int tid = threadIdx.x;
  const int lane = tid & 63, wave = tid >> 6;
  const int l15 = lane & 15, quad = lane >> 4;
  const int n0 = blockIdx.x << 4;
  const bool bd = (flags & FLAG_BD) != 0, s4 = (flags & FLAG_S4) != 0;

  int Keff = K, aCol0 = 0, ldB = N, wn0 = n0;
  const float* Wb = W;
  if (bd) {
    const int h = n0 >> 8;
    Keff = 256; aCol0 = h << 8; Wb = W + (size_t)h * 65536; ldB = 256; wn0 = n0 & 255;
  }
  const int kchunk = Keff >> 2;
  const int kbeg = wave * kchunk, kend = kbeg + kchunk;

  f32x4 acc0{}, acc1{}, acc2{}, acc3{};
  for (int k = kbeg; k < kend; k += 32) {
    const int kk = k + quad * 8;
    bf16x8 bfrag;
    if (s4) {
      const float* wp = W + ((size_t)(wn0 + l15) * 2048 + kk) * 4 + 3;
#pragma unroll
      for (int j = 0; j < 8; ++j) bfrag[j] = (bf16)wp[j * 4];
    } else {
      const float* wp = Wb + (size_t)kk * ldB + wn0 + l15;
#pragma unroll
      for (int j = 0; j < 8; ++j) bfrag[j] = (bf16)wp[(size_t)j * ldB];
    }
    const bf16* ap = A + (size_t)l15 * ldA + aCol0 + kk;
    const size_t st = (size_t)16 * ldA;
    bf16x8 a0 = *(const bf16x8*)(ap);
    bf16x8 a1 = *(const bf16x8*)(ap + st);
    bf16x8 a2 = *(const bf16x8*)(ap + 2 * st);
    bf16x8 a3 = *(const bf16x8*)(ap + 3 * st);
    acc0 = mfma_bf16_16x16x32(a0, bfrag, acc0);
    acc1 = mfma_bf16_16x16x32(a1, bfrag, acc1);
    acc2 = mfma_bf16_16x16x32(a2, bfrag, acc2);
    acc3 = mfma_bf16_16x16x32(a3, bfrag, acc3);
  }
  __shared__ float lds[4][64][20];  // row stride 20 floats: avoids bank conflicts
#pragma unroll
  for (int r = 0; r < 4; ++r) {
    const int rr = quad * 4 + r;  // C/D layout: row = quad*4+reg, col = lane&15
    lds[wave][rr][l15]      = acc0[r];
    lds[wave][16 + rr][l15] = acc1[r];
    lds[wave][32 + rr][l15] = acc2[r];
    lds[wave][48 + rr][l15] = acc3[r];
  }
  __syncthreads();
  const int col = tid & 15, rb = (tid >> 4) << 2;
  const float bv = bias[n0 + col];
#pragma unroll
  for (int r2 = 0; r2 < 4; ++r2) {
    const int row = rb + r2;
    float v = lds[0][row][col] + lds[1][row][col] + lds[2][row][col] + lds[3][row][col] + bv;
    if (mode == M_SILU)       v = v / (1.f + expf(-v));
    else if (mode == M_SIG)   v = 1.f / (1.f + expf(-v));
    else if (mode == M_SCALE) v *= 0.0625f;  // 1/sqrt(256), applied after bias (matches ref)
    else if (mode == M_FINAL) v += xadd[(size_t)row * N + n0 + col];
    const size_t oi = (size_t)row * N + n0 + col;
    if (outF) outF[oi] = v;
    if (outB) outB[oi] = (bf16)v;
  }
}

// ---------------------------------------------------------------------------
// i_t/f_t GEMV + stabilized gates + m_t output (all f32)
// ---------------------------------------------------------------------------
__global__ __launch_bounds__(256) void gates_kernel(
    const bf16* __restrict__ xc, const float* __restrict__ Wi, const float* __restrict__ bi,
    const float* __restrict__ Wf, const float* __restrict__ bfv, const float* __restrict__ m_prev,
    float* __restrict__ ig, float* __restrict__ fg, float* __restrict__ mt_out) {
  const int b = blockIdx.x, tid = threadIdx.x;
  float ai[8] = {}, af[8] = {};
  for (int k = tid; k < 2048; k += 256) {
    const float xv = (float)xc[b * 2048 + k];
    const float4 wi0 = *(const float4*)(Wi + (size_t)k * 8);
    const float4 wi1 = *(const float4*)(Wi + (size_t)k * 8 + 4);
    const float4 wf0 = *(const float4*)(Wf + (size_t)k * 8);
    const float4 wf1 = *(const float4*)(Wf + (size_t)k * 8 + 4);
    ai[0] += xv * wi0.x; ai[1] += xv * wi0.y; ai[2] += xv * wi0.z; ai[3] += xv * wi0.w;
    ai[4] += xv * wi1.x; ai[5] += xv * wi1.y; ai[6] += xv * wi1.z; ai[7] += xv * wi1.w;
    af[0] += xv * wf0.x; af[1] += xv * wf0.y; af[2] += xv * wf0.z; af[3] += xv * wf0.w;
    af[4] += xv * wf1.x; af[5] += xv * wf1.y; af[6] += xv * wf1.z; af[7] += xv * wf1.w;
  }
  __shared__ float ri[256][8], rf[256][8];
#pragma unroll
  for (int h = 0; h < 8; ++h) { ri[tid][h] = ai[h]; rf[tid][h] = af[h]; }
  __syncthreads();
  for (int off = 128; off; off >>= 1) {
    if (tid < off) {
#pragma unroll
      for (int h = 0; h < 8; ++h) { ri[tid][h] += ri[tid + off][h]; rf[tid][h] += rf[tid + off][h]; }
    }
    __syncthreads();
  }
  if (tid < 8) {
    const float it = ri[0][tid] + bi[tid];
    const float ft = rf[0][tid] + bfv[tid];
    const float mp = m_prev[b * 8 + tid];
    const float mt = fmaxf(ft + mp, it);
    mt_out[b * 8 + tid] = mt;
    ig[b * 8 + tid] = expf(it - mt);
    fg[b * 8 + tid] = expf(ft + mp - mt);
  }
}

// ---------------------------------------------------------------------------
// Fused state update (pure f32): c_t / n_t / den / num / h_t / GroupNorm /
// pre = (gn*gnw+gnb + x_skip) * silu(xr).  One block per (b,h).
// Wave-per-row c_prev streaming (float4, coalesced) + shfl reduce for num.
// ---------------------------------------------------------------------------
__global__ __launch_bounds__(256) void state_kernel(
    const float* __restrict__ c_prev, const float* __restrict__ n_prev,
    const float* __restrict__ qf, const float* __restrict__ kf,
    const float* __restrict__ vf, const float* __restrict__ of,
    const float* __restrict__ ig, const float* __restrict__ fg,
    const float* __restrict__ xskip, const float* __restrict__ xrf,
    const float* __restrict__ gnw, const float* __restrict__ gnb,
    float* __restrict__ ct_out, float* __restrict__ nt_out,
    float* __restrict__ ht_out, bf16* __restrict__ pre_bf) {
  const int bh = blockIdx.x, b = bh >> 3, h = bh & 7;
  const int tid = threadIdx.x, lane = tid & 63, wave = tid >> 6;
  const int vb = b * 2048 + h * 256;

  __shared__ float q_s[256], k_s[256], v_s[256], num_s[256], red[256];

  const float i_g = ig[bh], f_g = fg[bh];
  const float kv = kf[vb + tid], qv = qf[vb + tid];
  q_s[tid] = qv; k_s[tid] = kv; v_s[tid] = vf[vb + tid];
  const float nv = f_g * n_prev[bh * 256 + tid] + i_g * kv;
  nt_out[bh * 256 + tid] = nv;
  red[tid] = nv * qv;
  __syncthreads();
  for (int off = 128; off; off >>= 1) { if (tid < off) red[tid] += red[tid + off]; __syncthreads(); }
  const float den = fmaxf(red[0], 1.0f);

  // c_t update + num[row] = sum_k c_t[row][k]*q[k]; wave handles 64 rows.
  const size_t cb = (size_t)bh << 16;
  const int c0 = lane << 2;  // float4 column base
  const float qx = q_s[c0], qy = q_s[c0 + 1], qz = q_s[c0 + 2], qw = q_s[c0 + 3];
  const float kx = k_s[c0], ky = k_s[c0 + 1], kz = k_s[c0 + 2], kw = k_s[c0 + 3];
  for (int r = 0; r < 64; ++r) {
    const int row = (wave << 6) + r;
    const float vd = v_s[row];
    const size_t off = cb + ((size_t)row << 8) + c0;
    const float4 cp = *(const float4*)(c_prev + off);
    float4 cn;
    cn.x = f_g * cp.x + i_g * kx * vd;
    cn.y = f_g * cp.y + i_g * ky * vd;
    cn.z = f_g * cp.z + i_g * kz * vd;
    cn.w = f_g * cp.w + i_g * kw * vd;
    *(float4*)(ct_out + off) = cn;
    float p = cn.x * qx + cn.y * qy + cn.z * qz + cn.w * qw;
#pragma unroll
    for (int m = 32; m; m >>= 1) p += __shfl_xor(p, m, 64);
    if (lane == 0) num_s[row] = p;
  }
  __syncthreads();

  const float num = num_s[tid];
  const float hv = of[vb + tid] * num / den;
  ht_out[bh * 256 + tid] = hv;

  // GroupNorm over the 256 elements of this head
  __syncthreads();
  red[tid] = hv; __syncthreads();
  for (int off = 128; off; off >>= 1) { if (tid < off) red[tid] += red[tid + off]; __syncthreads(); }
  const float mu = red[0] * (1.f / 256.f);
  __syncthreads();
  const float dv = hv - mu;
  red[tid] = dv * dv; __syncthreads();
  for (int off = 128; off; off >>= 1) { if (tid < off) red[tid] += red[tid + off]; __syncthreads(); }
  const float gn = (hv - mu) * rsqrtf(red[0] * (1.f / 256.f) + 1e-5f);

  const int j = h * 256 + tid;
  const float xr = xrf[b * 2048 + j];
  const float pre = (gn * gnw[j] + gnb[j] + xskip[b * 2048 + j]) * (xr / (1.f + expf(-xr)));
  pre_bf[b * 2048 + j] = (bf16)pre;
}

// ---------------------------------------------------------------------------
extern "C" void kernel_launch(void* const* d_in, const int* in_sizes, int n_in,
                              void* d_out, int out_size, void* d_ws, size_t ws_size,
                              hipStream_t stream) {
  (void)in_sizes; (void)n_in; (void)out_size; (void)ws_size;
  const float* x      = (const float*)d_in[0];
  const float* c_prev = (const float*)d_in[2];
  const float* n_prev = (const float*)d_in[3];
  const float* m_prev = (const float*)d_in[4];
  const float* ln_w = (const float*)d_in[5];
  const float* ln_b = (const float*)d_in[6];
  const float* W_ul = (const float*)d_in[7];
  const float* b_ul = (const float*)d_in[8];
  const float* W_ur = (const float*)d_in[9];
  const float* b_ur = (const float*)d_in[10];
  const float* W_conv = (const float*)d_in[11];
  const float* b_conv = (const float*)d_in[12];
  const float* W_skip = (const float*)d_in[13];
  const float* b_skip = (const float*)d_in[14];
  const float* W_q = (const float*)d_in[15];
  const float* b_q = (const float*)d_in[16];
  const float* W_k = (const float*)d_in[17];
  const float* b_k = (const float*)d_in[18];
  const float* W_v = (const float*)d_in[19];
  const float* b_v = (const float*)d_in[20];
  const float* W_i = (const float*)d_in[21];
  const float* b_i = (const float*)d_in[22];
  const float* W_f = (const float*)d_in[23];
  const float* b_f = (const float*)d_in[24];
  const float* W_o = (const float*)d_in[25];
  const float* b_o = (const float*)d_in[26];
  const float* W_down = (const float*)d_in[27];
  const float* b_down = (const float*)d_in[28];
  const float* gn_w = (const float*)d_in[29];
  const float* gn_b = (const float*)d_in[30];

  // d_out layout (f32 elements): final | h_t | c_t | n_t | m_t
  float* out_final = (float*)d_out;
  float* out_ht = out_final + 65536;
  float* out_ct = out_final + 196608;
  float* out_nt = out_final + 33751040;
  float* out_mt = out_final + 33882112;

  char* ws = (char*)d_ws;
  bf16*  xn_bf   = (bf16*)(ws + 0);         // 128 KB
  bf16*  xl_bf   = (bf16*)(ws + 131072);    // 256 KB
  bf16*  xc_bf   = (bf16*)(ws + 393216);    // 256 KB
  bf16*  pre_bf  = (bf16*)(ws + 655360);    // 256 KB
  float* xr_f    = (float*)(ws + 917504);   // 512 KB
  float* xskip_f = (float*)(ws + 1441792);  // 512 KB
  float* q_f     = (float*)(ws + 1966080);
  float* k_f     = (float*)(ws + 2490368);
  float* v_f     = (float*)(ws + 3014656);
  float* o_f     = (float*)(ws + 3538944);
  float* ig_f    = (float*)(ws + 4063232);  // 2 KB
  float* fg_f    = (float*)(ws + 4065280);  // 2 KB

  ln_kernel<<<64, 256, 0, stream>>>(x, ln_w, ln_b, xn_bf);
  gemm_sk<<<128, 256, 0, stream>>>(xn_bf, W_ul, b_ul, nullptr, nullptr, xl_bf, 1024, 2048, 1024, M_NONE, 0);
  gemm_sk<<<128, 256, 0, stream>>>(xn_bf, W_ur, b_ur, nullptr, xr_f, nullptr, 1024, 2048, 1024, M_NONE, 0);
  gemm_sk<<<128, 256, 0, stream>>>(xl_bf, W_conv, b_conv, nullptr, nullptr, xc_bf, 2048, 2048, 2048, M_SILU, FLAG_S4);
  gemm_sk<<<128, 256, 0, stream>>>(xc_bf, W_skip, b_skip, nullptr, xskip_f, nullptr, 2048, 2048, 2048, M_NONE, 0);
  gemm_sk<<<128, 256, 0, stream>>>(xc_bf, W_q, b_q, nullptr, q_f, nullptr, 256, 2048, 2048, M_NONE, FLAG_BD);
  gemm_sk<<<128, 256, 0, stream>>>(xc_bf, W_k, b_k, nullptr, k_f, nullptr, 256, 2048, 2048, M_SCALE, FLAG_BD);
  gemm_sk<<<128, 256, 0, stream>>>(xl_bf, W_v, b_v, nullptr, v_f, nullptr, 256, 2048, 2048, M_NONE, FLAG_BD);
  gemm_sk<<<128, 256, 0, stream>>>(xl_bf, W_o, b_o, nullptr, o_f, nullptr, 2048, 2048, 2048, M_SIG, 0);
  gates_kernel<<<64, 256, 0, stream>>>(xc_bf, W_i, b_i, W_f, b_f, m_prev, ig_f, fg_f, out_mt);
  state_kernel<<<512, 256, 0, stream>>>(c_prev, n_prev, q_f, k_f, v_f, o_f, ig_f, fg_f,
                                        xskip_f, xr_f, gn_w, gn_b, out_ct, out_nt, out_ht, pre_bf);
  gemm_sk<<<64, 256, 0, stream>>>(pre_bf, W_down, b_down, x, out_final, nullptr, 2048, 1024, 2048, M_FINAL, 0);
}

// Round 4
// 448.807 us; speedup vs baseline: 1.1627x; 1.1627x over previous
//
#include <hip/hip_runtime.h>
#include <cstddef>

typedef __bf16 bf16;
typedef __bf16 bf16x8 __attribute__((ext_vector_type(8)));
typedef short  s16x8  __attribute__((ext_vector_type(8)));
typedef float  f32x4  __attribute__((ext_vector_type(4)));

// ---------------------------------------------------------------------------
// MFMA wrapper robust to builtin operand type (__bf16 vector vs short vector)
// ---------------------------------------------------------------------------
template <class T> T&& declv() noexcept;
template <class, class = void> struct takes_bf16vec { static constexpr bool value = false; };
template <class V> struct takes_bf16vec<V, decltype((void)__builtin_amdgcn_mfma_f32_16x16x32_bf16(
    declv<V>(), declv<V>(), declv<f32x4>(), 0, 0, 0))> { static constexpr bool value = true; };

template <class V>
__device__ __forceinline__ f32x4 mfma_bf16_16x16x32(V a, V b, f32x4 c) {
  if constexpr (takes_bf16vec<V>::value) {
    return __builtin_amdgcn_mfma_f32_16x16x32_bf16(a, b, c, 0, 0, 0);
  } else {
    return __builtin_amdgcn_mfma_f32_16x16x32_bf16(
        __builtin_bit_cast(s16x8, a), __builtin_bit_cast(s16x8, b), c, 0, 0, 0);
  }
}

constexpr int M_NONE = 0, M_SILU = 1, M_SIG = 2, M_SCALE = 3, M_FINAL = 4;

// ---------------------------------------------------------------------------
// LayerNorm: x[64][1024] f32 -> xn bf16
// ---------------------------------------------------------------------------
__global__ __launch_bounds__(256) void ln_kernel(const float* __restrict__ x,
                                                 const float* __restrict__ w,
                                                 const float* __restrict__ bs,
                                                 bf16* __restrict__ xn) {
  const int b = blockIdx.x, tid = threadIdx.x;
  __shared__ float red[256];
  float vals[4];
  float s = 0.f;
#pragma unroll
  for (int i = 0; i < 4; ++i) { vals[i] = x[b * 1024 + i * 256 + tid]; s += vals[i]; }
  red[tid] = s; __syncthreads();
  for (int off = 128; off; off >>= 1) { if (tid < off) red[tid] += red[tid + off]; __syncthreads(); }
  const float mu = red[0] * (1.f / 1024.f);
  __syncthreads();
  float s2 = 0.f;
#pragma unroll
  for (int i = 0; i < 4; ++i) { const float d = vals[i] - mu; s2 += d * d; }
  red[tid] = s2; __syncthreads();
  for (int off = 128; off; off >>= 1) { if (tid < off) red[tid] += red[tid + off]; __syncthreads(); }
  const float rs = rsqrtf(red[0] * (1.f / 1024.f) + 1e-5f);
#pragma unroll
  for (int i = 0; i < 4; ++i) {
    const int j = i * 256 + tid;
    xn[b * 1024 + j] = (bf16)((vals[i] - mu) * rs * w[j] + bs[j]);
  }
}

// ---------------------------------------------------------------------------
// Split-K partial GEMM: part[ks][64][Ncomb] = A[64][K-slice] @ B-slice
//   DUAL: two weight/A segments of 128 tiles each (Ncomb = 4096)
//   S4:   B[n][k] = W[(n*2048+k)*4 + 3]  (conv tap)
// grid = NTILES * KS blocks; compile-time K -> fully unrolled inner loop.
// ---------------------------------------------------------------------------
template <int K, int KS, int NTILES, bool S4, bool DUAL>
__global__ __launch_bounds__(256) void gemm_part(
    const bf16* __restrict__ A0, const bf16* __restrict__ A1,
    const float* __restrict__ W0, const float* __restrict__ W1,
    int ldA, int ldB, float* __restrict__ part) {
  constexpr int Ncomb = NTILES * 16;
  constexpr int Kslice = K / KS;
  constexpr int chunk = Kslice / 4;
  const int tid = threadIdx.x;
  const int lane = tid & 63, wave = tid >> 6;
  const int l15 = lane & 15, quad = lane >> 4;
  const int tile = blockIdx.x % NTILES, ks = blockIdx.x / NTILES;

  const bf16* A = A0;
  const float* W = W0;
  int ncol;
  if (DUAL) {
    const int seg = tile >> 7;
    if (seg) { A = A1; W = W1; }
    ncol = (tile & 127) * 16;
  } else {
    ncol = tile * 16;
  }
  const int kbeg = ks * Kslice + wave * chunk;

  f32x4 acc0{}, acc1{}, acc2{}, acc3{};
#pragma unroll
  for (int k = 0; k < chunk; k += 32) {
    const int kk = kbeg + k + quad * 8;
    bf16x8 bfrag;
    if (S4) {
      const float* wp = W + ((size_t)(ncol + l15) * 2048 + kk) * 4 + 3;
#pragma unroll
      for (int j = 0; j < 8; ++j) bfrag[j] = (bf16)wp[j * 4];
    } else {
      const float* wp = W + (size_t)kk * ldB + ncol + l15;
#pragma unroll
      for (int j = 0; j < 8; ++j) bfrag[j] = (bf16)wp[(size_t)j * ldB];
    }
    const bf16* ap = A + (size_t)l15 * ldA + kk;
    const size_t st = (size_t)16 * ldA;
    bf16x8 a0 = *(const bf16x8*)(ap);
    bf16x8 a1 = *(const bf16x8*)(ap + st);
    bf16x8 a2 = *(const bf16x8*)(ap + 2 * st);
    bf16x8 a3 = *(const bf16x8*)(ap + 3 * st);
    acc0 = mfma_bf16_16x16x32(a0, bfrag, acc0);
    acc1 = mfma_bf16_16x16x32(a1, bfrag, acc1);
    acc2 = mfma_bf16_16x16x32(a2, bfrag, acc2);
    acc3 = mfma_bf16_16x16x32(a3, bfrag, acc3);
  }
  __shared__ float lds[4][64][20];
#pragma unroll
  for (int r = 0; r < 4; ++r) {
    const int rr = quad * 4 + r;  // C/D: row = quad*4+reg, col = lane&15
    lds[wave][rr][l15]      = acc0[r];
    lds[wave][16 + rr][l15] = acc1[r];
    lds[wave][32 + rr][l15] = acc2[r];
    lds[wave][48 + rr][l15] = acc3[r];
  }
  __syncthreads();
  const int col = tid & 15, rb = (tid >> 4) << 2;
#pragma unroll
  for (int r2 = 0; r2 < 4; ++r2) {
    const int row = rb + r2;
    const float v = lds[0][row][col] + lds[1][row][col] + lds[2][row][col] + lds[3][row][col];
    part[((size_t)ks * 64 + row) * Ncomb + tile * 16 + col] = v;
  }
}

// ---------------------------------------------------------------------------
// Combine split-K partials: sum KS slices, +bias, activation, write f32/bf16.
// Two independent halves (for fused dual GEMMs).
// ---------------------------------------------------------------------------
__global__ __launch_bounds__(256) void combine(
    const float* __restrict__ part, int KS, int Ncomb, int halfN,
    const float* __restrict__ bias0, const float* __restrict__ bias1,
    int mode0, int mode1,
    float* __restrict__ outF0, bf16* __restrict__ outB0,
    float* __restrict__ outF1, bf16* __restrict__ outB1,
    const float* __restrict__ xadd) {
  const int e = (blockIdx.x * 256 + threadIdx.x) * 4;
  const int total = 64 * Ncomb;
  if (e >= total) return;
  const int row = e / Ncomb, col = e - row * Ncomb;
  float4 s = *(const float4*)(part + e);
  for (int ks = 1; ks < KS; ++ks) {
    const float4 p = *(const float4*)(part + (size_t)ks * total + e);
    s.x += p.x; s.y += p.y; s.z += p.z; s.w += p.w;
  }
  const int seg = (col >= halfN) ? 1 : 0;
  const int cn = col - seg * halfN;
  const float* bias = seg ? bias1 : bias0;
  const int mode = seg ? mode1 : mode0;
  float* outF = seg ? outF1 : outF0;
  bf16* outB = seg ? outB1 : outB0;
  float vv[4] = {s.x, s.y, s.z, s.w};
#pragma unroll
  for (int j = 0; j < 4; ++j) {
    float v = vv[j] + bias[cn + j];
    if (mode == M_SILU)       v = v / (1.f + expf(-v));
    else if (mode == M_SIG)   v = 1.f / (1.f + expf(-v));
    else if (mode == M_SCALE) v *= 0.0625f;
    else if (mode == M_FINAL) v += xadd[(size_t)row * halfN + cn + j];
    const size_t oi = (size_t)row * halfN + cn + j;
    if (outF) outF[oi] = v;
    if (outB) outB[oi] = (bf16)v;
  }
}

// ---------------------------------------------------------------------------
// Fused block-diagonal q/k/v GEMM (K=256 per head). grid = 384 tiles:
// [0,128)=q (A=xc), [128,256)=k (A=xc, *0.0625), [256,384)=v (A=xl).
// ---------------------------------------------------------------------------
__global__ __launch_bounds__(256) void gemm_qkv(
    const bf16* __restrict__ xc, const bf16* __restrict__ xl,
    const float* __restrict__ Wq, const float* __restrict__ bq,
    const float* __restrict__ Wk, const float* __restrict__ bk,
    const float* __restrict__ Wv, const float* __restrict__ bv,
    float* __restrict__ qf, float* __restrict__ kf, float* __restrict__ vf) {
  const int tid = threadIdx.x;
  const int lane = tid & 63, wave = tid >> 6;
  const int l15 = lane & 15, quad = lane >> 4;
  const int seg = blockIdx.x >> 7, t = blockIdx.x & 127;
  const int n0 = t * 16, h = t >> 4, wn0 = n0 & 255;
  const bf16* A = (seg == 2) ? xl : xc;
  const float* W = (seg == 0) ? Wq : (seg == 1) ? Wk : Wv;
  const float* bias = (seg == 0) ? bq : (seg == 1) ? bk : bv;
  float* out = (seg == 0) ? qf : (seg == 1) ? kf : vf;
  const float* Wb = W + (size_t)h * 65536;
  const int aCol0 = h << 8;
  const int kbeg = wave * 64;

  f32x4 acc0{}, acc1{}, acc2{}, acc3{};
#pragma unroll
  for (int k = 0; k < 64; k += 32) {
    const int kk = kbeg + k + quad * 8;
    bf16x8 bfrag;
    const float* wp = Wb + (size_t)kk * 256 + wn0 + l15;
#pragma unroll
    for (int j = 0; j < 8; ++j) bfrag[j] = (bf16)wp[(size_t)j * 256];
    const bf16* ap = A + (size_t)l15 * 2048 + aCol0 + kk;
    const size_t st = (size_t)16 * 2048;
    bf16x8 a0 = *(const bf16x8*)(ap);
    bf16x8 a1 = *(const bf16x8*)(ap + st);
    bf16x8 a2 = *(const bf16x8*)(ap + 2 * st);
    bf16x8 a3 = *(const bf16x8*)(ap + 3 * st);
    acc0 = mfma_bf16_16x16x32(a0, bfrag, acc0);
    acc1 = mfma_bf16_16x16x32(a1, bfrag, acc1);
    acc2 = mfma_bf16_16x16x32(a2, bfrag, acc2);
    acc3 = mfma_bf16_16x16x32(a3, bfrag, acc3);
  }
  __shared__ float lds[4][64][20];
#pragma unroll
  for (int r = 0; r < 4; ++r) {
    const int rr = quad * 4 + r;
    lds[wave][rr][l15]      = acc0[r];
    lds[wave][16 + rr][l15] = acc1[r];
    lds[wave][32 + rr][l15] = acc2[r];
    lds[wave][48 + rr][l15] = acc3[r];
  }
  __syncthreads();
  const int col = tid & 15, rb = (tid >> 4) << 2;
  const float bv_ = bias[n0 + col];
#pragma unroll
  for (int r2 = 0; r2 < 4; ++r2) {
    const int row = rb + r2;
    float v = lds[0][row][col] + lds[1][row][col] + lds[2][row][col] + lds[3][row][col] + bv_;
    if (seg == 1) v *= 0.0625f;
    out[(size_t)row * 2048 + n0 + col] = v;
  }
}

// ---------------------------------------------------------------------------
// Direct GEMM with epilogue (used for W_down; grid = N/16)
// ---------------------------------------------------------------------------
__global__ __launch_bounds__(256) void gemm_sk(
    const bf16* __restrict__ A, const float* __restrict__ W,
    const float* __restrict__ bias, const float* __restrict__ xadd,
    float* __restrict__ outF, bf16* __restrict__ outB,
    int K, int N, int ldA, int mode) {
  const int tid = threadIdx.x;
  const int lane = tid & 63, wave = tid >> 6;
  const int l15 = lane & 15, quad = lane >> 4;
  const int n0 = blockIdx.x << 4;
  const int ldB = N;
  const int kchunk = K >> 2;
  const int kbeg = wave * kchunk, kend = kbeg + kchunk;

  f32x4 acc0{}, acc1{}, acc2{}, acc3{};
  for (int k = kbeg; k < kend; k += 32) {
    const int kk = k + quad * 8;
    bf16x8 bfrag;
    const float* wp = W + (size_t)kk * ldB + n0 + l15;
#pragma unroll
    for (int j = 0; j < 8; ++j) bfrag[j] = (bf16)wp[(size_t)j * ldB];
    const bf16* ap = A + (size_t)l15 * ldA + kk;
    const size_t st = (size_t)16 * ldA;
    bf16x8 a0 = *(const bf16x8*)(ap);
    bf16x8 a1 = *(const bf16x8*)(ap + st);
    bf16x8 a2 = *(const bf16x8*)(ap + 2 * st);
    bf16x8 a3 = *(const bf16x8*)(ap + 3 * st);
    acc0 = mfma_bf16_16x16x32(a0, bfrag, acc0);
    acc1 = mfma_bf16_16x16x32(a1, bfrag, acc1);
    acc2 = mfma_bf16_16x16x32(a2, bfrag, acc2);
    acc3 = mfma_bf16_16x16x32(a3, bfrag, acc3);
  }
  __shared__ float lds[4][64][20];
#pragma unroll
  for (int r = 0; r < 4; ++r) {
    const int rr = quad * 4 + r;
    lds[wave][rr][l15]      = acc0[r];
    lds[wave][16 + rr][l15] = acc1[r];
    lds[wave][32 + rr][l15] = acc2[r];
    lds[wave][48 + rr][l15] = acc3[r];
  }
  __syncthreads();
  const int col = tid & 15, rb = (tid >> 4) << 2;
  const float bv = bias[n0 + col];
#pragma unroll
  for (int r2 = 0; r2 < 4; ++r2) {
    const int row = rb + r2;
    float v = lds[0][row][col] + lds[1][row][col] + lds[2][row][col] + lds[3][row][col] + bv;
    if (mode == M_FINAL) v += xadd[(size_t)row * N + n0 + col];
    const size_t oi = (size_t)row * N + n0 + col;
    if (outF) outF[oi] = v;
    if (outB) outB[oi] = (bf16)v;
  }
}

// ---------------------------------------------------------------------------
// i_t/f_t GEMV + stabilized gates + m_t output
// ---------------------------------------------------------------------------
__global__ __launch_bounds__(256) void gates_kernel(
    const bf16* __restrict__ xc, const float* __restrict__ Wi, const float* __restrict__ bi,
    const float* __restrict__ Wf, const float* __restrict__ bfv, const float* __restrict__ m_prev,
    float* __restrict__ ig, float* __restrict__ fg, float* __restrict__ mt_out) {
  const int b = blockIdx.x, tid = threadIdx.x;
  float ai[8] = {}, af[8] = {};
  for (int k = tid; k < 2048; k += 256) {
    const float xv = (float)xc[b * 2048 + k];
    const float4 wi0 = *(const float4*)(Wi + (size_t)k * 8);
    const float4 wi1 = *(const float4*)(Wi + (size_t)k * 8 + 4);
    const float4 wf0 = *(const float4*)(Wf + (size_t)k * 8);
    const float4 wf1 = *(const float4*)(Wf + (size_t)k * 8 + 4);
    ai[0] += xv * wi0.x; ai[1] += xv * wi0.y; ai[2] += xv * wi0.z; ai[3] += xv * wi0.w;
    ai[4] += xv * wi1.x; ai[5] += xv * wi1.y; ai[6] += xv * wi1.z; ai[7] += xv * wi1.w;
    af[0] += xv * wf0.x; af[1] += xv * wf0.y; af[2] += xv * wf0.z; af[3] += xv * wf0.w;
    af[4] += xv * wf1.x; af[5] += xv * wf1.y; af[6] += xv * wf1.z; af[7] += xv * wf1.w;
  }
  __shared__ float ri[256][8], rf[256][8];
#pragma unroll
  for (int h = 0; h < 8; ++h) { ri[tid][h] = ai[h]; rf[tid][h] = af[h]; }
  __syncthreads();
  for (int off = 128; off; off >>= 1) {
    if (tid < off) {
#pragma unroll
      for (int h = 0; h < 8; ++h) { ri[tid][h] += ri[tid + off][h]; rf[tid][h] += rf[tid + off][h]; }
    }
    __syncthreads();
  }
  if (tid < 8) {
    const float it = ri[0][tid] + bi[tid];
    const float ft = rf[0][tid] + bfv[tid];
    const float mp = m_prev[b * 8 + tid];
    const float mt = fmaxf(ft + mp, it);
    mt_out[b * 8 + tid] = mt;
    ig[b * 8 + tid] = expf(it - mt);
    fg[b * 8 + tid] = expf(ft + mp - mt);
  }
}

// ---------------------------------------------------------------------------
// state1: c_t = f*c_prev + i*v⊗k, num[row] = c_t[row]·q.
// grid 4096 (8 blocks per (b,h) x 512 pairs; 32 rows/block; 8 threads/row).
// ---------------------------------------------------------------------------
__global__ __launch_bounds__(256) void state1(
    const float* __restrict__ c_prev, const float* __restrict__ qf,
    const float* __restrict__ kf, const float* __restrict__ vf,
    const float* __restrict__ ig, const float* __restrict__ fg,
    float* __restrict__ ct_out, float* __restrict__ numw) {
  const int bh = blockIdx.x >> 3, rg = blockIdx.x & 7;  // bh in [0,512)
  const int tid = threadIdx.x;
  const int b = bh >> 3, h = bh & 7, vb = b * 2048 + h * 256;
  __shared__ float q_s[256], k_s[256];
  q_s[tid] = qf[vb + tid];
  k_s[tid] = kf[vb + tid];
  __syncthreads();
  const float i_g = ig[bh], f_g = fg[bh];
  const int row = rg * 32 + (tid >> 3);
  const int lane8 = tid & 7;
  const float vd = vf[vb + row];
  const float iv = i_g * vd;
  const size_t base = ((size_t)bh << 16) + ((size_t)row << 8) + lane8 * 4;
  float p = 0.f;
#pragma unroll
  for (int i = 0; i < 8; ++i) {
    const int c = lane8 * 4 + i * 32;
    const float4 cp = *(const float4*)(c_prev + base + i * 32);
    float4 cn;
    cn.x = f_g * cp.x + iv * k_s[c];
    cn.y = f_g * cp.y + iv * k_s[c + 1];
    cn.z = f_g * cp.z + iv * k_s[c + 2];
    cn.w = f_g * cp.w + iv * k_s[c + 3];
    *(float4*)(ct_out + base + i * 32) = cn;
    p += cn.x * q_s[c] + cn.y * q_s[c + 1] + cn.z * q_s[c + 2] + cn.w * q_s[c + 3];
  }
#pragma unroll
  for (int m = 1; m < 8; m <<= 1) p += __shfl_xor(p, m, 64);
  if (lane8 == 0) numw[bh * 256 + row] = p;
}

// ---------------------------------------------------------------------------
// state2: n_t, den, h_t, GroupNorm, pre = (gn*w+b + skip)*silu(xr). 1 blk/(b,h).
// NOTE: numw and ht_out may be the SAME buffer (num read at [i] strictly
// before ht written at [i] by the same thread) — no __restrict__ on them.
// ---------------------------------------------------------------------------
__global__ __launch_bounds__(256) void state2(
    const float* __restrict__ n_prev, const float* __restrict__ qf,
    const float* __restrict__ kf, const float* __restrict__ of,
    const float* __restrict__ ig, const float* __restrict__ fg,
    const float* numw, const float* __restrict__ xskip,
    const float* __restrict__ xrf, const float* __restrict__ gnw,
    const float* __restrict__ gnb, float* __restrict__ nt_out,
    float* ht_out, bf16* __restrict__ pre_bf) {
  const int bh = blockIdx.x, b = bh >> 3, h = bh & 7;
  const int tid = threadIdx.x;
  const int vb = b * 2048 + h * 256;
  __shared__ float red[256];
  const float i_g = ig[bh], f_g = fg[bh];
  const float qv = qf[vb + tid], kv = kf[vb + tid];
  const float nv = f_g * n_prev[bh * 256 + tid] + i_g * kv;
  nt_out[bh * 256 + tid] = nv;
  red[tid] = nv * qv;
  __syncthreads();
  for (int off = 128; off; off >>= 1) { if (tid < off) red[tid] += red[tid + off]; __syncthreads(); }
  const float den = fmaxf(red[0], 1.0f);
  const float num = numw[bh * 256 + tid];
  const float hv = of[vb + tid] * num / den;
  ht_out[bh * 256 + tid] = hv;
  __syncthreads();
  red[tid] = hv; __syncthreads();
  for (int off = 128; off; off >>= 1) { if (tid < off) red[tid] += red[tid + off]; __syncthreads(); }
  const float mu = red[0] * (1.f / 256.f);
  __syncthreads();
  const float dv = hv - mu;
  red[tid] = dv * dv; __syncthreads();
  for (int off = 128; off; off >>= 1) { if (tid < off) red[tid] += red[tid + off]; __syncthreads(); }
  const float gn = (hv - mu) * rsqrtf(red[0] * (1.f / 256.f) + 1e-5f);
  const int j = h * 256 + tid;
  const float xr = xrf[b * 2048 + j];
  const float pre = (gn * gnw[j] + gnb[j] + xskip[b * 2048 + j]) * (xr / (1.f + expf(-xr)));
  pre_bf[b * 2048 + j] = (bf16)pre;
}

// ---------------------------------------------------------------------------
extern "C" void kernel_launch(void* const* d_in, const int* in_sizes, int n_in,
                              void* d_out, int out_size, void* d_ws, size_t ws_size,
                              hipStream_t stream) {
  (void)in_sizes; (void)n_in; (void)out_size; (void)ws_size;
  const float* x      = (const float*)d_in[0];
  const float* c_prev = (const float*)d_in[2];
  const float* n_prev = (const float*)d_in[3];
  const float* m_prev = (const float*)d_in[4];
  const float* ln_w = (const float*)d_in[5];
  const float* ln_b = (const float*)d_in[6];
  const float* W_ul = (const float*)d_in[7];
  const float* b_ul = (const float*)d_in[8];
  const float* W_ur = (const float*)d_in[9];
  const float* b_ur = (const float*)d_in[10];
  const float* W_conv = (const float*)d_in[11];
  const float* b_conv = (const float*)d_in[12];
  const float* W_skip = (const float*)d_in[13];
  const float* b_skip = (const float*)d_in[14];
  const float* W_q = (const float*)d_in[15];
  const float* b_q = (const float*)d_in[16];
  const float* W_k = (const float*)d_in[17];
  const float* b_k = (const float*)d_in[18];
  const float* W_v = (const float*)d_in[19];
  const float* b_v = (const float*)d_in[20];
  const float* W_i = (const float*)d_in[21];
  const float* b_i = (const float*)d_in[22];
  const float* W_f = (const float*)d_in[23];
  const float* b_f = (const float*)d_in[24];
  const float* W_o = (const float*)d_in[25];
  const float* b_o = (const float*)d_in[26];
  const float* W_down = (const float*)d_in[27];
  const float* b_down = (const float*)d_in[28];
  const float* gn_w = (const float*)d_in[29];
  const float* gn_b = (const float*)d_in[30];

  // d_out layout (f32 elements): final | h_t | c_t | n_t | m_t
  float* out_final = (float*)d_out;
  float* out_ht = out_final + 65536;
  float* out_ct = out_final + 196608;
  float* out_nt = out_final + 33751040;
  float* out_mt = out_final + 33882112;

  char* ws = (char*)d_ws;
  bf16*  xn_bf   = (bf16*)(ws + 0);         // 128 KB
  bf16*  xl_bf   = (bf16*)(ws + 131072);    // 256 KB
  bf16*  xc_bf   = (bf16*)(ws + 393216);    // 256 KB
  bf16*  pre_bf  = (bf16*)(ws + 655360);    // 256 KB
  float* xr_f    = (float*)(ws + 917504);   // 512 KB
  float* xskip_f = (float*)(ws + 1441792);  // 512 KB
  float* q_f     = (float*)(ws + 1966080);
  float* k_f     = (float*)(ws + 2490368);
  float* v_f     = (float*)(ws + 3014656);
  float* o_f     = (float*)(ws + 3538944);
  float* ig_f    = (float*)(ws + 4063232);  // 2 KB
  float* fg_f    = (float*)(ws + 4065280);  // 2 KB  (ws usage ends 4,067,328 B)
  // num staged in the h_t output region (written by state1, consumed+overwritten
  // elementwise by state2 — same-thread read-before-write at identical index).
  float* num_f   = out_ht;
  // Split-K partials staged in the not-yet-written c_t output region (134 MB;
  // partials use <= 4 MB, all consumed before state1 writes real c_t).
  float* part    = out_ct;

  ln_kernel<<<64, 256, 0, stream>>>(x, ln_w, ln_b, xn_bf);
  // ul+ur fused: N=4096, K=1024, KS=4 -> grid 1024
  gemm_part<1024, 4, 256, false, true><<<1024, 256, 0, stream>>>(
      xn_bf, xn_bf, W_ul, W_ur, 1024, 2048, part);
  combine<<<256, 256, 0, stream>>>(part, 4, 4096, 2048, b_ul, b_ur, M_NONE, M_NONE,
                                   nullptr, xl_bf, xr_f, nullptr, nullptr);
  // conv tap GEMM: N=2048, K=2048, KS=8 -> grid 1024
  gemm_part<2048, 8, 128, true, false><<<1024, 256, 0, stream>>>(
      xl_bf, nullptr, W_conv, nullptr, 2048, 2048, part);
  combine<<<128, 256, 0, stream>>>(part, 8, 2048, 2048, b_conv, nullptr, M_SILU, M_NONE,
                                   nullptr, xc_bf, nullptr, nullptr, nullptr);
  // skip (A=xc) + o (A=xl) fused: N=4096, K=2048, KS=4 -> grid 1024
  gemm_part<2048, 4, 256, false, true><<<1024, 256, 0, stream>>>(
      xc_bf, xl_bf, W_skip, W_o, 2048, 2048, part);
  combine<<<256, 256, 0, stream>>>(part, 4, 4096, 2048, b_skip, b_o, M_NONE, M_SIG,
                                   xskip_f, nullptr, o_f, nullptr, nullptr);
  gemm_qkv<<<384, 256, 0, stream>>>(xc_bf, xl_bf, W_q, b_q, W_k, b_k, W_v, b_v,
                                    q_f, k_f, v_f);
  gates_kernel<<<64, 256, 0, stream>>>(xc_bf, W_i, b_i, W_f, b_f, m_prev, ig_f, fg_f, out_mt);
  state1<<<4096, 256, 0, stream>>>(c_prev, q_f, k_f, v_f, ig_f, fg_f, out_ct, num_f);
  state2<<<512, 256, 0, stream>>>(n_prev, q_f, k_f, o_f, ig_f, fg_f, num_f,
                                  xskip_f, xr_f, gn_w, gn_b, out_nt, out_ht, pre_bf);
  gemm_sk<<<64, 256, 0, stream>>>(pre_bf, W_down, b_down, x, out_final, nullptr,
                                  2048, 1024, 2048, M_FINAL);
}

// Round 5
// 438.018 us; speedup vs baseline: 1.1914x; 1.0246x over previous
//
#include <hip/hip_runtime.h>
#include <cstddef>

typedef __bf16 bf16;
typedef __bf16 bf16x8 __attribute__((ext_vector_type(8)));
typedef short  s16x8  __attribute__((ext_vector_type(8)));
typedef float  f32x4  __attribute__((ext_vector_type(4)));

// ---------------------------------------------------------------------------
// MFMA wrapper robust to builtin operand type (__bf16 vector vs short vector)
// ---------------------------------------------------------------------------
template <class T> T&& declv() noexcept;
template <class, class = void> struct takes_bf16vec { static constexpr bool value = false; };
template <class V> struct takes_bf16vec<V, decltype((void)__builtin_amdgcn_mfma_f32_16x16x32_bf16(
    declv<V>(), declv<V>(), declv<f32x4>(), 0, 0, 0))> { static constexpr bool value = true; };

template <class V>
__device__ __forceinline__ f32x4 mfma_bf16_16x16x32(V a, V b, f32x4 c) {
  if constexpr (takes_bf16vec<V>::value) {
    return __builtin_amdgcn_mfma_f32_16x16x32_bf16(a, b, c, 0, 0, 0);
  } else {
    return __builtin_amdgcn_mfma_f32_16x16x32_bf16(
        __builtin_bit_cast(s16x8, a), __builtin_bit_cast(s16x8, b), c, 0, 0, 0);
  }
}

constexpr int M_NONE = 0, M_SILU = 1, M_SIG = 2;

// ---------------------------------------------------------------------------
// Repack W_conv[:,:,3] ([n][k][4] f32) -> contiguous bf16 [n][k].
// float4-coalesced read (67 MB streamed once), keep .w.
// ---------------------------------------------------------------------------
__global__ __launch_bounds__(256) void repack_wc(const float* __restrict__ Wc,
                                                 bf16* __restrict__ Wp) {
  const int n = blockIdx.x;
  const float4* src = (const float4*)(Wc + (size_t)n * 8192);
  bf16* dst = Wp + (size_t)n * 2048;
  for (int k = threadIdx.x; k < 2048; k += 256) {
    const float4 t = src[k];           // taps 0..3 of (n,k); tap3 = .w
    dst[k] = (bf16)t.w;
  }
}

// ---------------------------------------------------------------------------
// LayerNorm: x[64][1024] f32 -> xn bf16.  Also initializes
// out_final[b][j] = x[b][j] + b_down[j]  (base for the atomic W_down GEMM).
// ---------------------------------------------------------------------------
__global__ __launch_bounds__(256) void ln_kernel(const float* __restrict__ x,
                                                 const float* __restrict__ w,
                                                 const float* __restrict__ bs,
                                                 const float* __restrict__ bdown,
                                                 bf16* __restrict__ xn,
                                                 float* __restrict__ outf) {
  const int b = blockIdx.x, tid = threadIdx.x;
  __shared__ float red[256];
  float vals[4];
  float s = 0.f;
#pragma unroll
  for (int i = 0; i < 4; ++i) { vals[i] = x[b * 1024 + i * 256 + tid]; s += vals[i]; }
  red[tid] = s; __syncthreads();
  for (int off = 128; off; off >>= 1) { if (tid < off) red[tid] += red[tid + off]; __syncthreads(); }
  const float mu = red[0] * (1.f / 1024.f);
  __syncthreads();
  float s2 = 0.f;
#pragma unroll
  for (int i = 0; i < 4; ++i) { const float d = vals[i] - mu; s2 += d * d; }
  red[tid] = s2; __syncthreads();
  for (int off = 128; off; off >>= 1) { if (tid < off) red[tid] += red[tid + off]; __syncthreads(); }
  const float rs = rsqrtf(red[0] * (1.f / 1024.f) + 1e-5f);
#pragma unroll
  for (int i = 0; i < 4; ++i) {
    const int j = i * 256 + tid;
    xn[b * 1024 + j] = (bf16)((vals[i] - mu) * rs * w[j] + bs[j]);
    outf[b * 1024 + j] = vals[i] + bdown[j];   // final-residual base
  }
}

// ---------------------------------------------------------------------------
// Split-K partial GEMM: part[ks][64][Ncomb] = A[64][K-slice] @ B-slice
//   DUAL:   two A/W segments of 128 tiles each (Ncomb = 4096)
//   BT:     B is bf16 [N][K] (repacked conv weight) -> dwordx4 fragment loads
//   ATOMIC: atomicAdd block result into out[row*outN + n] (no partials)
// grid = NTILES * KS; compile-time K -> fully unrolled inner loop.
// ---------------------------------------------------------------------------
template <int K, int KS, int NTILES, bool BT, bool DUAL, bool ATOMIC>
__global__ __launch_bounds__(256) void gemm_part(
    const bf16* __restrict__ A0, const bf16* __restrict__ A1,
    const float* __restrict__ W0, const float* __restrict__ W1,
    const bf16* __restrict__ Wb,
    int ldA, int ldB, float* __restrict__ dst, int outN) {
  constexpr int Ncomb = NTILES * 16;
  constexpr int Kslice = K / KS;
  constexpr int chunk = Kslice / 4;
  const int tid = threadIdx.x;
  const int lane = tid & 63, wave = tid >> 6;
  const int l15 = lane & 15, quad = lane >> 4;
  const int tile = blockIdx.x % NTILES, ks = blockIdx.x / NTILES;

  const bf16* A = A0;
  const float* W = W0;
  int ncol;
  if (DUAL) {
    const int seg = tile >> 7;
    if (seg) { A = A1; W = W1; }
    ncol = (tile & 127) * 16;
  } else {
    ncol = tile * 16;
  }
  const int kbeg = ks * Kslice + wave * chunk;

  f32x4 acc0{}, acc1{}, acc2{}, acc3{};
#pragma unroll
  for (int k = 0; k < chunk; k += 32) {
    const int kk = kbeg + k + quad * 8;
    bf16x8 bfrag;
    if (BT) {
      bfrag = *(const bf16x8*)(Wb + (size_t)(ncol + l15) * K + kk);
    } else {
      const float* wp = W + (size_t)kk * ldB + ncol + l15;
#pragma unroll
      for (int j = 0; j < 8; ++j) bfrag[j] = (bf16)wp[(size_t)j * ldB];
    }
    const bf16* ap = A + (size_t)l15 * ldA + kk;
    const size_t st = (size_t)16 * ldA;
    bf16x8 a0 = *(const bf16x8*)(ap);
    bf16x8 a1 = *(const bf16x8*)(ap + st);
    bf16x8 a2 = *(const bf16x8*)(ap + 2 * st);
    bf16x8 a3 = *(const bf16x8*)(ap + 3 * st);
    acc0 = mfma_bf16_16x16x32(a0, bfrag, acc0);
    acc1 = mfma_bf16_16x16x32(a1, bfrag, acc1);
    acc2 = mfma_bf16_16x16x32(a2, bfrag, acc2);
    acc3 = mfma_bf16_16x16x32(a3, bfrag, acc3);
  }
  __shared__ float lds[4][64][20];
#pragma unroll
  for (int r = 0; r < 4; ++r) {
    const int rr = quad * 4 + r;  // C/D: row = quad*4+reg, col = lane&15
    lds[wave][rr][l15]      = acc0[r];
    lds[wave][16 + rr][l15] = acc1[r];
    lds[wave][32 + rr][l15] = acc2[r];
    lds[wave][48 + rr][l15] = acc3[r];
  }
  __syncthreads();
  const int col = tid & 15, rb = (tid >> 4) << 2;
#pragma unroll
  for (int r2 = 0; r2 < 4; ++r2) {
    const int row = rb + r2;
    const float v = lds[0][row][col] + lds[1][row][col] + lds[2][row][col] + lds[3][row][col];
    if (ATOMIC) {
      atomicAdd(dst + (size_t)row * outN + tile * 16 + col, v);
    } else {
      dst[((size_t)ks * 64 + row) * Ncomb + tile * 16 + col] = v;
    }
  }
}

// ---------------------------------------------------------------------------
// Combine split-K partials: sum KS slices, +bias, activation, write f32/bf16.
// Two independent halves (for fused dual GEMMs).
// ---------------------------------------------------------------------------
__global__ __launch_bounds__(256) void combine(
    const float* __restrict__ part, int KS, int Ncomb, int halfN,
    const float* __restrict__ bias0, const float* __restrict__ bias1,
    int mode0, int mode1,
    float* __restrict__ outF0, bf16* __restrict__ outB0,
    float* __restrict__ outF1, bf16* __restrict__ outB1) {
  const int e = (blockIdx.x * 256 + threadIdx.x) * 4;
  const int total = 64 * Ncomb;
  if (e >= total) return;
  const int row = e / Ncomb, col = e - row * Ncomb;
  float4 s = *(const float4*)(part + e);
  for (int ks = 1; ks < KS; ++ks) {
    const float4 p = *(const float4*)(part + (size_t)ks * total + e);
    s.x += p.x; s.y += p.y; s.z += p.z; s.w += p.w;
  }
  const int seg = (col >= halfN) ? 1 : 0;
  const int cn = col - seg * halfN;
  const float* bias = seg ? bias1 : bias0;
  const int mode = seg ? mode1 : mode0;
  float* outF = seg ? outF1 : outF0;
  bf16* outB = seg ? outB1 : outB0;
  float vv[4] = {s.x, s.y, s.z, s.w};
#pragma unroll
  for (int j = 0; j < 4; ++j) {
    float v = vv[j] + bias[cn + j];
    if (mode == M_SILU)       v = v / (1.f + expf(-v));
    else if (mode == M_SIG)   v = 1.f / (1.f + expf(-v));
    const size_t oi = (size_t)row * halfN + cn + j;
    if (outF) outF[oi] = v;
    if (outB) outB[oi] = (bf16)v;
  }
}

// ---------------------------------------------------------------------------
// Fused block-diagonal q/k/v GEMM (K=256 per head). grid = 384 tiles:
// [0,128)=q (A=xc), [128,256)=k (A=xc, *0.0625), [256,384)=v (A=xl).
// ---------------------------------------------------------------------------
__global__ __launch_bounds__(256) void gemm_qkv(
    const bf16* __restrict__ xc, const bf16* __restrict__ xl,
    const float* __restrict__ Wq, const float* __restrict__ bq,
    const float* __restrict__ Wk, const float* __restrict__ bk,
    const float* __restrict__ Wv, const float* __restrict__ bv,
    float* __restrict__ qf, float* __restrict__ kf, float* __restrict__ vf) {
  const int tid = threadIdx.x;
  const int lane = tid & 63, wave = tid >> 6;
  const int l15 = lane & 15, quad = lane >> 4;
  const int seg = blockIdx.x >> 7, t = blockIdx.x & 127;
  const int n0 = t * 16, h = t >> 4, wn0 = n0 & 255;
  const bf16* A = (seg == 2) ? xl : xc;
  const float* W = (seg == 0) ? Wq : (seg == 1) ? Wk : Wv;
  const float* bias = (seg == 0) ? bq : (seg == 1) ? bk : bv;
  float* out = (seg == 0) ? qf : (seg == 1) ? kf : vf;
  const float* Wb = W + (size_t)h * 65536;
  const int aCol0 = h << 8;
  const int kbeg = wave * 64;

  f32x4 acc0{}, acc1{}, acc2{}, acc3{};
#pragma unroll
  for (int k = 0; k < 64; k += 32) {
    const int kk = kbeg + k + quad * 8;
    bf16x8 bfrag;
    const float* wp = Wb + (size_t)kk * 256 + wn0 + l15;
#pragma unroll
    for (int j = 0; j < 8; ++j) bfrag[j] = (bf16)wp[(size_t)j * 256];
    const bf16* ap = A + (size_t)l15 * 2048 + aCol0 + kk;
    const size_t st = (size_t)16 * 2048;
    bf16x8 a0 = *(const bf16x8*)(ap);
    bf16x8 a1 = *(const bf16x8*)(ap + st);
    bf16x8 a2 = *(const bf16x8*)(ap + 2 * st);
    bf16x8 a3 = *(const bf16x8*)(ap + 3 * st);
    acc0 = mfma_bf16_16x16x32(a0, bfrag, acc0);
    acc1 = mfma_bf16_16x16x32(a1, bfrag, acc1);
    acc2 = mfma_bf16_16x16x32(a2, bfrag, acc2);
    acc3 = mfma_bf16_16x16x32(a3, bfrag, acc3);
  }
  __shared__ float lds[4][64][20];
#pragma unroll
  for (int r = 0; r < 4; ++r) {
    const int rr = quad * 4 + r;
    lds[wave][rr][l15]      = acc0[r];
    lds[wave][16 + rr][l15] = acc1[r];
    lds[wave][32 + rr][l15] = acc2[r];
    lds[wave][48 + rr][l15] = acc3[r];
  }
  __syncthreads();
  const int col = tid & 15, rb = (tid >> 4) << 2;
  const float bv_ = bias[n0 + col];
#pragma unroll
  for (int r2 = 0; r2 < 4; ++r2) {
    const int row = rb + r2;
    float v = lds[0][row][col] + lds[1][row][col] + lds[2][row][col] + lds[3][row][col] + bv_;
    if (seg == 1) v *= 0.0625f;
    out[(size_t)row * 2048 + n0 + col] = v;
  }
}

// ---------------------------------------------------------------------------
// i_t/f_t GEMV + stabilized gates + m_t output
// ---------------------------------------------------------------------------
__global__ __launch_bounds__(256) void gates_kernel(
    const bf16* __restrict__ xc, const float* __restrict__ Wi, const float* __restrict__ bi,
    const float* __restrict__ Wf, const float* __restrict__ bfv, const float* __restrict__ m_prev,
    float* __restrict__ ig, float* __restrict__ fg, float* __restrict__ mt_out) {
  const int b = blockIdx.x, tid = threadIdx.x;
  float ai[8] = {}, af[8] = {};
  for (int k = tid; k < 2048; k += 256) {
    const float xv = (float)xc[b * 2048 + k];
    const float4 wi0 = *(const float4*)(Wi + (size_t)k * 8);
    const float4 wi1 = *(const float4*)(Wi + (size_t)k * 8 + 4);
    const float4 wf0 = *(const float4*)(Wf + (size_t)k * 8);
    const float4 wf1 = *(const float4*)(Wf + (size_t)k * 8 + 4);
    ai[0] += xv * wi0.x; ai[1] += xv * wi0.y; ai[2] += xv * wi0.z; ai[3] += xv * wi0.w;
    ai[4] += xv * wi1.x; ai[5] += xv * wi1.y; ai[6] += xv * wi1.z; ai[7] += xv * wi1.w;
    af[0] += xv * wf0.x; af[1] += xv * wf0.y; af[2] += xv * wf0.z; af[3] += xv * wf0.w;
    af[4] += xv * wf1.x; af[5] += xv * wf1.y; af[6] += xv * wf1.z; af[7] += xv * wf1.w;
  }
  __shared__ float ri[256][8], rf[256][8];
#pragma unroll
  for (int h = 0; h < 8; ++h) { ri[tid][h] = ai[h]; rf[tid][h] = af[h]; }
  __syncthreads();
  for (int off = 128; off; off >>= 1) {
    if (tid < off) {
#pragma unroll
      for (int h = 0; h < 8; ++h) { ri[tid][h] += ri[tid + off][h]; rf[tid][h] += rf[tid + off][h]; }
    }
    __syncthreads();
  }
  if (tid < 8) {
    const float it = ri[0][tid] + bi[tid];
    const float ft = rf[0][tid] + bfv[tid];
    const float mp = m_prev[b * 8 + tid];
    const float mt = fmaxf(ft + mp, it);
    mt_out[b * 8 + tid] = mt;
    ig[b * 8 + tid] = expf(it - mt);
    fg[b * 8 + tid] = expf(ft + mp - mt);
  }
}

// ---------------------------------------------------------------------------
// state1: c_t = f*c_prev + i*v⊗k, num[row] = c_t[row]·q.
// grid 4096 (8 blocks per (b,h) x 512 pairs; 32 rows/block; 8 threads/row).
// ---------------------------------------------------------------------------
__global__ __launch_bounds__(256) void state1(
    const float* __restrict__ c_prev, const float* __restrict__ qf,
    const float* __restrict__ kf, const float* __restrict__ vf,
    const float* __restrict__ ig, const float* __restrict__ fg,
    float* __restrict__ ct_out, float* __restrict__ numw) {
  const int bh = blockIdx.x >> 3, rg = blockIdx.x & 7;  // bh in [0,512)
  const int tid = threadIdx.x;
  const int b = bh >> 3, h = bh & 7, vb = b * 2048 + h * 256;
  __shared__ float q_s[256], k_s[256];
  q_s[tid] = qf[vb + tid];
  k_s[tid] = kf[vb + tid];
  __syncthreads();
  const float i_g = ig[bh], f_g = fg[bh];
  const int row = rg * 32 + (tid >> 3);
  const int lane8 = tid & 7;
  const float vd = vf[vb + row];
  const float iv = i_g * vd;
  const size_t base = ((size_t)bh << 16) + ((size_t)row << 8) + lane8 * 4;
  float p = 0.f;
#pragma unroll
  for (int i = 0; i < 8; ++i) {
    const int c = lane8 * 4 + i * 32;
    const float4 cp = *(const float4*)(c_prev + base + i * 32);
    float4 cn;
    cn.x = f_g * cp.x + iv * k_s[c];
    cn.y = f_g * cp.y + iv * k_s[c + 1];
    cn.z = f_g * cp.z + iv * k_s[c + 2];
    cn.w = f_g * cp.w + iv * k_s[c + 3];
    *(float4*)(ct_out + base + i * 32) = cn;
    p += cn.x * q_s[c] + cn.y * q_s[c + 1] + cn.z * q_s[c + 2] + cn.w * q_s[c + 3];
  }
#pragma unroll
  for (int m = 1; m < 8; m <<= 1) p += __shfl_xor(p, m, 64);
  if (lane8 == 0) numw[bh * 256 + row] = p;
}

// ---------------------------------------------------------------------------
// state2: n_t, den, h_t, GroupNorm, pre = (gn*w+b + skip)*silu(xr). 1 blk/(b,h).
// numw and ht_out may alias (same-thread read-before-write at same index).
// ---------------------------------------------------------------------------
__global__ __launch_bounds__(256) void state2(
    const float* __restrict__ n_prev, const float* __restrict__ qf,
    const float* __restrict__ kf, const float* __restrict__ of,
    const float* __restrict__ ig, const float* __restrict__ fg,
    const float* numw, const float* __restrict__ xskip,
    const float* __restrict__ xrf, const float* __restrict__ gnw,
    const float* __restrict__ gnb, float* __restrict__ nt_out,
    float* ht_out, bf16* __restrict__ pre_bf) {
  const int bh = blockIdx.x, b = bh >> 3, h = bh & 7;
  const int tid = threadIdx.x;
  const int vb = b * 2048 + h * 256;
  __shared__ float red[256];
  const float i_g = ig[bh], f_g = fg[bh];
  const float qv = qf[vb + tid], kv = kf[vb + tid];
  const float nv = f_g * n_prev[bh * 256 + tid] + i_g * kv;
  nt_out[bh * 256 + tid] = nv;
  red[tid] = nv * qv;
  __syncthreads();
  for (int off = 128; off; off >>= 1) { if (tid < off) red[tid] += red[tid + off]; __syncthreads(); }
  const float den = fmaxf(red[0], 1.0f);
  const float num = numw[bh * 256 + tid];
  const float hv = of[vb + tid] * num / den;
  ht_out[bh * 256 + tid] = hv;
  __syncthreads();
  red[tid] = hv; __syncthreads();
  for (int off = 128; off; off >>= 1) { if (tid < off) red[tid] += red[tid + off]; __syncthreads(); }
  const float mu = red[0] * (1.f / 256.f);
  __syncthreads();
  const float dv = hv - mu;
  red[tid] = dv * dv; __syncthreads();
  for (int off = 128; off; off >>= 1) { if (tid < off) red[tid] += red[tid + off]; __syncthreads(); }
  const float gn = (hv - mu) * rsqrtf(red[0] * (1.f / 256.f) + 1e-5f);
  const int j = h * 256 + tid;
  const float xr = xrf[b * 2048 + j];
  const float pre = (gn * gnw[j] + gnb[j] + xskip[b * 2048 + j]) * (xr / (1.f + expf(-xr)));
  pre_bf[b * 2048 + j] = (bf16)pre;
}

// ---------------------------------------------------------------------------
extern "C" void kernel_launch(void* const* d_in, const int* in_sizes, int n_in,
                              void* d_out, int out_size, void* d_ws, size_t ws_size,
                              hipStream_t stream) {
  (void)in_sizes; (void)n_in; (void)out_size; (void)ws_size;
  const float* x      = (const float*)d_in[0];
  const float* c_prev = (const float*)d_in[2];
  const float* n_prev = (const float*)d_in[3];
  const float* m_prev = (const float*)d_in[4];
  const float* ln_w = (const float*)d_in[5];
  const float* ln_b = (const float*)d_in[6];
  const float* W_ul = (const float*)d_in[7];
  const float* b_ul = (const float*)d_in[8];
  const float* W_ur = (const float*)d_in[9];
  const float* b_ur = (const float*)d_in[10];
  const float* W_conv = (const float*)d_in[11];
  const float* b_conv = (const float*)d_in[12];
  const float* W_skip = (const float*)d_in[13];
  const float* b_skip = (const float*)d_in[14];
  const float* W_q = (const float*)d_in[15];
  const float* b_q = (const float*)d_in[16];
  const float* W_k = (const float*)d_in[17];
  const float* b_k = (const float*)d_in[18];
  const float* W_v = (const float*)d_in[19];
  const float* b_v = (const float*)d_in[20];
  const float* W_i = (const float*)d_in[21];
  const float* b_i = (const float*)d_in[22];
  const float* W_f = (const float*)d_in[23];
  const float* b_f = (const float*)d_in[24];
  const float* W_o = (const float*)d_in[25];
  const float* b_o = (const float*)d_in[26];
  const float* W_down = (const float*)d_in[27];
  const float* b_down = (const float*)d_in[28];
  const float* gn_w = (const float*)d_in[29];
  const float* gn_b = (const float*)d_in[30];

  // d_out layout (f32 elements): final | h_t | c_t | n_t | m_t
  float* out_final = (float*)d_out;
  float* out_ht = out_final + 65536;
  float* out_ct = out_final + 196608;
  float* out_nt = out_final + 33751040;
  float* out_mt = out_final + 33882112;

  char* ws = (char*)d_ws;
  bf16*  xn_bf   = (bf16*)(ws + 0);         // 128 KB
  bf16*  xl_bf   = (bf16*)(ws + 131072);    // 256 KB
  bf16*  xc_bf   = (bf16*)(ws + 393216);    // 256 KB
  bf16*  pre_bf  = (bf16*)(ws + 655360);    // 256 KB
  float* xr_f    = (float*)(ws + 917504);   // 512 KB
  float* xskip_f = (float*)(ws + 1441792);  // 512 KB
  float* q_f     = (float*)(ws + 1966080);
  float* k_f     = (float*)(ws + 2490368);
  float* v_f     = (float*)(ws + 3014656);
  float* o_f     = (float*)(ws + 3538944);
  float* ig_f    = (float*)(ws + 4063232);  // 2 KB
  float* fg_f    = (float*)(ws + 4065280);  // 2 KB
  bf16*  wcp     = (bf16*)(ws + 4067328);   // 8 MB repacked conv tap (ws ~517 MB per fill counter)
  // num staged in the h_t output region (state1 writes, state2 reads then overwrites).
  float* num_f   = out_ht;
  // Split-K partials staged in the not-yet-written c_t output region.
  float* part    = out_ct;

  repack_wc<<<2048, 256, 0, stream>>>(W_conv, wcp);
  ln_kernel<<<64, 256, 0, stream>>>(x, ln_w, ln_b, b_down, xn_bf, out_final);
  // ul+ur fused: N=4096, K=1024, KS=4 -> grid 1024
  gemm_part<1024, 4, 256, false, true, false><<<1024, 256, 0, stream>>>(
      xn_bf, xn_bf, W_ul, W_ur, nullptr, 1024, 2048, part, 0);
  combine<<<256, 256, 0, stream>>>(part, 4, 4096, 2048, b_ul, b_ur, M_NONE, M_NONE,
                                   nullptr, xl_bf, xr_f, nullptr);
  // conv tap GEMM (repacked bf16 [N][K]): N=2048, K=2048, KS=8 -> grid 1024
  gemm_part<2048, 8, 128, true, false, false><<<1024, 256, 0, stream>>>(
      xl_bf, nullptr, nullptr, nullptr, wcp, 2048, 2048, part, 0);
  combine<<<128, 256, 0, stream>>>(part, 8, 2048, 2048, b_conv, nullptr, M_SILU, M_NONE,
                                   nullptr, xc_bf, nullptr, nullptr);
  // skip (A=xc) + o (A=xl) fused: N=4096, K=2048, KS=4 -> grid 1024
  gemm_part<2048, 4, 256, false, true, false><<<1024, 256, 0, stream>>>(
      xc_bf, xl_bf, W_skip, W_o, nullptr, 2048, 2048, part, 0);
  combine<<<256, 256, 0, stream>>>(part, 4, 4096, 2048, b_skip, b_o, M_NONE, M_SIG,
                                   xskip_f, nullptr, o_f, nullptr);
  gemm_qkv<<<384, 256, 0, stream>>>(xc_bf, xl_bf, W_q, b_q, W_k, b_k, W_v, b_v,
                                    q_f, k_f, v_f);
  gates_kernel<<<64, 256, 0, stream>>>(xc_bf, W_i, b_i, W_f, b_f, m_prev, ig_f, fg_f, out_mt);
  state1<<<4096, 256, 0, stream>>>(c_prev, q_f, k_f, v_f, ig_f, fg_f, out_ct, num_f);
  state2<<<512, 256, 0, stream>>>(n_prev, q_f, k_f, o_f, ig_f, fg_f, num_f,
                                  xskip_f, xr_f, gn_w, gn_b, out_nt, out_ht, pre_bf);
  // W_down: split-K atomic into out_final (base = x + b_down from ln_kernel).
  gemm_part<2048, 8, 64, false, false, true><<<512, 256, 0, stream>>>(
      pre_bf, nullptr, W_down, nullptr, nullptr, 2048, 1024, out_final, 1024);
}